// Round 8
// baseline (311.862 us; speedup 1.0000x reference)
//
#include <hip/hip_runtime.h>
#include <stdint.h>

typedef __attribute__((ext_vector_type(8))) short short8;
typedef __attribute__((ext_vector_type(4))) float f32x4;

#define DEV static __device__ __forceinline__

DEV float b2f(unsigned short u) { union { float f; unsigned int i; } x; x.i = ((unsigned int)u) << 16; return x.f; }
DEV unsigned short f2b(float f) {
    union { float f; unsigned int i; } x; x.f = f;
    unsigned int r = x.i + 0x7fffu + ((x.i >> 16) & 1u);
    return (unsigned short)(r >> 16);
}
DEV void gld_lds16(const void* g, void* l) {
    __builtin_amdgcn_global_load_lds((const __attribute__((address_space(1))) void*)g,
                                     (__attribute__((address_space(3))) void*)l, 16, 0, 0);
}
DEV int xcd_swizzle(int bid, int nwg) {
    int q = nwg >> 3, r = nwg & 7;
    int xcd = bid & 7, base = bid >> 3;
    return (xcd < r ? xcd * (q + 1) : r * (q + 1) + (xcd - r) * q) + base;
}

__global__ void cast3_kernel(const float* __restrict__ a, unsigned short* __restrict__ oa, long na8,
                             const float* __restrict__ b, unsigned short* __restrict__ ob_, long nb8,
                             const float* __restrict__ c, unsigned short* __restrict__ oc, long nc8) {
    long i = (long)blockIdx.x * blockDim.x + threadIdx.x;
    long stride = (long)gridDim.x * blockDim.x;
    long tot = na8 + nb8 + nc8;
    for (; i < tot; i += stride) {
        const float* src; unsigned short* dst; long j = i;
        if (j < na8) { src = a; dst = oa; }
        else if (j < na8 + nb8) { j -= na8; src = b; dst = ob_; }
        else { j -= na8 + nb8; src = c; dst = oc; }
        const f32x4* p = (const f32x4*)(src + j * 8);
        f32x4 v0 = p[0], v1 = p[1];
        short8 o;
        o[0] = (short)f2b(v0[0]); o[1] = (short)f2b(v0[1]); o[2] = (short)f2b(v0[2]); o[3] = (short)f2b(v0[3]);
        o[4] = (short)f2b(v1[0]); o[5] = (short)f2b(v1[1]); o[6] = (short)f2b(v1[2]); o[7] = (short)f2b(v1[3]);
        *(short8*)(dst + j * 8) = o;
    }
}

// NT GEMM, 128x128 tile, BK=64, double-buffered counted-vmcnt pipeline.
// OMODE 0: f32 C natural.
// OMODE 1: bf16 C natural (LDS-coalesced store).
// OMODE 3: bf16 C TRANSPOSED (C_T[n][m]) + f32 aux write for cols>=4352 (dtraw[t][32]).
//          [R8: swizzled transposed LDS tile T[ch][mrow^((ch&15)<<3)] — kills 3.9M bank conflicts]
// OMODE 4: f32 C natural, row-scaled by rsqrt(aux[row]/2048 + eps).
template<int OMODE>
__global__ __launch_bounds__(256) void gemm_nt(
    const unsigned short* __restrict__ A, int lda, long sAy, long sAz,
    const unsigned short* __restrict__ B, int ldb, long sBy, long sBz,
    void* __restrict__ Cp, int ldc, long sCy, long sCz,
    float* __restrict__ aux,
    int M, int N, int K, int tn)
{
    A += (long)blockIdx.y * sAy + (long)blockIdx.z * sAz;
    B += (long)blockIdx.y * sBy + (long)blockIdx.z * sBz;
    int bid = xcd_swizzle(blockIdx.x, gridDim.x);
    int im = bid / tn, in_ = bid % tn;
    int m0 = im * 128, n0 = in_ * 128;
    __shared__ short smem[2 * 2 * 128 * 64];   // 64 KB
    int tid = threadIdx.x;
    int lane = tid & 63, wave = tid >> 6;
    int wu = __builtin_amdgcn_readfirstlane(wave);
    int wm = wave >> 1, wn = wave & 1;
    f32x4 acc[4][4];
#pragma unroll
    for (int m = 0; m < 4; m++)
#pragma unroll
        for (int n = 0; n < 4; n++) acc[m][n] = (f32x4){0.f, 0.f, 0.f, 0.f};

    auto stage = [&](int k0, int s) {
        short* As = smem + s * 16384;
        short* Bs = As + 8192;
#pragma unroll
        for (int i = 0; i < 4; ++i) {
            int g = i * 256 + tid;
            int r = g >> 3, pc = g & 7;
            int cc = pc ^ (r & 7);
            gld_lds16(A + (long)(m0 + r) * lda + k0 + cc * 8, As + (i * 256 + wu * 64) * 8);
            int rb = n0 + r; rb = rb < N ? rb : N - 1;
            gld_lds16(B + (long)rb * ldb + k0 + cc * 8, Bs + (i * 256 + wu * 64) * 8);
        }
    };

    int nt = K >> 6;
    stage(0, 0);
    for (int t = 0; t < nt; ++t) {
        int cur = t & 1;
        if (t + 1 < nt) {
            stage((t + 1) << 6, cur ^ 1);
            asm volatile("s_waitcnt vmcnt(8)" ::: "memory");
        } else {
            asm volatile("s_waitcnt vmcnt(0)" ::: "memory");
        }
        __builtin_amdgcn_s_barrier();
        const short* As = smem + cur * 16384;
        const short* Bs = As + 8192;
#pragma unroll
        for (int ks = 0; ks < 2; ++ks) {
            short8 af[4], bfr[4];
#pragma unroll
            for (int m = 0; m < 4; ++m) {
                int r = wm * 64 + m * 16 + (lane & 15);
                int pc = (ks * 4 + (lane >> 4)) ^ (r & 7);
                af[m] = *(const short8*)(As + r * 64 + pc * 8);
            }
#pragma unroll
            for (int n = 0; n < 4; ++n) {
                int r = wn * 64 + n * 16 + (lane & 15);
                int pc = (ks * 4 + (lane >> 4)) ^ (r & 7);
                bfr[n] = *(const short8*)(Bs + r * 64 + pc * 8);
            }
            __builtin_amdgcn_s_setprio(1);
#pragma unroll
            for (int m = 0; m < 4; ++m)
#pragma unroll
                for (int n = 0; n < 4; ++n)
                    acc[m][n] = __builtin_amdgcn_mfma_f32_16x16x32_bf16(af[m], bfr[n], acc[m][n], 0, 0, 0);
            __builtin_amdgcn_s_setprio(0);
        }
        __builtin_amdgcn_s_barrier();
    }

    int rbase = m0 + wm * 64 + ((lane >> 4) << 2);
    int cbase = n0 + wn * 64 + (lane & 15);
    if (OMODE == 0) {
        float* C = (float*)Cp;
        C += (long)blockIdx.y * sCy + (long)blockIdx.z * sCz;
#pragma unroll
        for (int m = 0; m < 4; ++m)
#pragma unroll
            for (int n = 0; n < 4; ++n) {
                int col = cbase + n * 16;
                if (col < N) {
#pragma unroll
                    for (int r = 0; r < 4; ++r)
                        C[(long)(rbase + m * 16 + r) * ldc + col] = acc[m][n][r];
                }
            }
    } else if (OMODE == 4) {
        float* C = (float*)Cp;
#pragma unroll
        for (int m = 0; m < 4; ++m)
#pragma unroll
            for (int r = 0; r < 4; ++r) {
                int row = rbase + m * 16 + r;
                float sc = rsqrtf(aux[row] * (1.f / 2048.f) + 1e-6f);
#pragma unroll
                for (int n = 0; n < 4; ++n)
                    C[(long)row * ldc + cbase + n * 16] = acc[m][n][r] * sc;
            }
    } else if (OMODE == 1) {
        unsigned short* Cs = (unsigned short*)smem;
        int rl = wm * 64 + ((lane >> 4) << 2);
        int cl = wn * 64 + (lane & 15);
#pragma unroll
        for (int m = 0; m < 4; ++m)
#pragma unroll
            for (int r = 0; r < 4; ++r) {
                int row = rl + m * 16 + r;
                int xr = ((row >> 2) & 3) << 4;
#pragma unroll
                for (int n = 0; n < 4; ++n)
                    Cs[row * 128 + ((cl + n * 16) ^ xr)] = f2b(acc[m][n][r]);
            }
        __syncthreads();
        unsigned short* C = (unsigned short*)Cp;
        C += (long)blockIdx.y * sCy + (long)blockIdx.z * sCz;
#pragma unroll
        for (int j = 0; j < 8; ++j) {
            int chunk = j * 256 + tid;
            int row = chunk >> 4, c8 = (chunk & 15) * 8;
            int col = n0 + c8;
            int xr = ((row >> 2) & 3) << 4;
            if (col < N)
                *(short8*)(C + (long)(m0 + row) * ldc + col) = *(const short8*)(Cs + row * 128 + (c8 ^ xr));
        }
    } else { // OMODE 3: transposed bf16 write via swizzled T[ch][mrow]
        if (OMODE == 3) {
            // dt columns written f32-exact
#pragma unroll
            for (int m = 0; m < 4; ++m)
#pragma unroll
                for (int n = 0; n < 4; ++n) {
                    int col = cbase + n * 16;
                    if (col >= 4352 && col < N) {
#pragma unroll
                        for (int r = 0; r < 4; ++r)
                            aux[(long)(rbase + m * 16 + r) * 32 + (col - 4352)] = acc[m][n][r];
                    }
                }
        }
        unsigned short* T = (unsigned short*)smem; // 128ch x 128m bf16 = 32KB
        int rl = wm * 64 + ((lane >> 4) << 2);
        int cl = wn * 64 + (lane & 15);
#pragma unroll
        for (int n = 0; n < 4; ++n) {
            int ch = cl + n * 16;
            int sw = (ch & 15) << 3;
#pragma unroll
            for (int m = 0; m < 4; ++m)
#pragma unroll
                for (int r = 0; r < 4; ++r) {
                    int mrow = rl + m * 16 + r;
                    T[ch * 128 + (mrow ^ sw)] = f2b(acc[m][n][r]);
                }
        }
        __syncthreads();
        unsigned short* C = (unsigned short*)Cp;
#pragma unroll
        for (int j = 0; j < 8; ++j) {
            int idx = j * 256 + tid;
            int ch = idx >> 4, mc8 = (idx & 15) * 8;
            int gch = n0 + ch;
            if (gch < N) {
                short8 o = *(const short8*)(T + ch * 128 + (mc8 ^ ((ch & 15) << 3)));
                *(short8*)(C + (long)gch * ldc + m0 + mc8) = o;
            }
        }
    }
}

// softplus(dt)+cumsum per (b,h): dtraw[t][32] f32 -> dtv, Acum, Atot
__global__ __launch_bounds__(256) void dtcum_kernel(
    const float* __restrict__ dtraw,
    const float* __restrict__ dt_bias, const float* __restrict__ A_log,
    float* __restrict__ dtv, float* __restrict__ Acum, float* __restrict__ Atot)
{
    int bh = blockIdx.x;
    int b = bh >> 5, h = bh & 31;
    int tid = threadIdx.x;
    float bias = dt_bias[h];
    float negA = -__expf(A_log[h]);
    __shared__ float s[256];
    for (int c = 0; c < 8; ++c) {
        int t = c * 256 + tid;
        float v = dtraw[(long)(b * 2048 + t) * 32 + h] + bias;
        float dt = v > 20.f ? v : log1pf(__expf(v));
        dtv[(long)bh * 2048 + t] = dt;
        s[tid] = dt * negA;
        __syncthreads();
        for (int off = 1; off < 256; off <<= 1) {
            float x = (tid >= off) ? s[tid - off] : 0.f;
            __syncthreads();
            s[tid] += x;
            __syncthreads();
        }
        Acum[(long)bh * 2048 + t] = s[tid];
        if (tid == 255) Atot[bh * 8 + c] = s[255];
        __syncthreads();
    }
}

// conv1d K=4 causal + SiLU in channel-major domain.
// grid: (8 chunks, 36 channel-tiles, 2 batches)
__global__ __launch_bounds__(256) void convT_kernel(
    const unsigned short* __restrict__ projT,
    const float* __restrict__ conv_w, const float* __restrict__ conv_b,
    const float* __restrict__ dtv, const float* __restrict__ Acum, const float* __restrict__ Atot,
    unsigned short* __restrict__ xdtT, unsigned short* __restrict__ xdtd,
    unsigned short* __restrict__ Bb, unsigned short* __restrict__ Cb, unsigned short* __restrict__ BT)
{
    int tt = blockIdx.x;       // 0..7
    int cht = blockIdx.y;      // 0..35
    int b = blockIdx.z;
    int t0 = tt * 256;
    int ch0 = cht * 64;
    int tid = threadIdx.x;
    __shared__ short raw[64 * 264];
    __shared__ unsigned short trsp[256 * 64];
    __shared__ float sdt[256], sac[256];
    __shared__ float satot;
    bool hidden = cht < 32;
    for (int j = 0; j < 9; ++j) {
        int idx = j * 256 + tid;
        if (idx < 64 * 33) {
            int r = idx / 33, cc = idx % 33;
            int tg = t0 - 8 + cc * 8;
            short8 v = {0, 0, 0, 0, 0, 0, 0, 0};
            if (tg >= 0)
                v = *(const short8*)(projT + (long)(2048 + ch0 + r) * 4096 + b * 2048 + tg);
            *(short8*)(raw + r * 264 + cc * 8) = v;
        }
    }
    if (hidden) {
        int h = cht;
        sdt[tid] = dtv[(long)(b * 32 + h) * 2048 + t0 + tid];
        sac[tid] = Acum[(long)(b * 32 + h) * 2048 + t0 + tid];
        if (tid == 0) satot = Atot[(b * 32 + h) * 8 + tt];
    }
    __syncthreads();
    for (int p = 0; p < 8; ++p) {
        int ch = p * 8 + (tid >> 5);
        int tb = (tid & 31) * 8;
        int cg = ch0 + ch;
        f32x4 wv = *(const f32x4*)(conv_w + cg * 4);
        float cb = conv_b[cg];
        float s[8];
#pragma unroll
        for (int j = 0; j < 8; ++j) {
            int tl = tb + j;
            float a = cb;
#pragma unroll
            for (int k = 0; k < 4; ++k)
                a += b2f((unsigned short)raw[ch * 264 + tl + 5 + k]) * wv[k];
            s[j] = a / (1.f + __expf(-a));
        }
        if (hidden) {
            short8 o1, o2;
#pragma unroll
            for (int j = 0; j < 8; ++j) {
                int tl = tb + j;
                float xdt = s[j] * sdt[tl];
                float dec = __expf(satot - sac[tl]);
                o1[j] = (short)f2b(xdt);
                o2[j] = (short)f2b(xdt * dec);
            }
            long off = (long)cg * 4096 + b * 2048 + t0 + tb;
            *(short8*)(xdtT + off) = o1;
            *(short8*)(xdtd + off) = o2;
        } else {
            short8 o;
#pragma unroll
            for (int j = 0; j < 8; ++j) o[j] = (short)f2b(s[j]);
            if (cht < 34) {
                int n = (cht - 32) * 64 + ch;
                *(short8*)(BT + (long)n * 4096 + b * 2048 + t0 + tb) = o;
            }
#pragma unroll
            for (int j = 0; j < 8; ++j) {
                int tl = tb + j;
                trsp[tl * 64 + (ch ^ ((tl & 7) << 3))] = (unsigned short)o[j];
            }
        }
    }
    if (!hidden) {
        __syncthreads();
        unsigned short* dst = (cht < 34) ? Bb : Cb;
        int n0 = ((cht - 32) & 1) * 64;
        for (int p = 0; p < 8; ++p) {
            int idx = p * 256 + tid;
            int tl = idx >> 3, c8 = (idx & 7) * 8;
            short8 o;
#pragma unroll
            for (int q = 0; q < 8; ++q)
                o[q] = (short)trsp[tl * 64 + ((c8 + q) ^ ((tl & 7) << 3))];
            *(short8*)(dst + (long)(b * 2048 + t0 + tl) * 128 + n0 + c8) = o;
        }
    }
}

// Fused Y_diag (+D folded into M diagonal) + Y_off + gate-SiLU + norm_w + ssq -> ynu[t][ch]
__global__ __launch_bounds__(256) void ydiagoff_kernel(
    const unsigned short* __restrict__ Gm,
    const float* __restrict__ Acum,
    const unsigned short* __restrict__ xdtT,
    const unsigned short* __restrict__ projT,
    const unsigned short* __restrict__ Cb,
    const unsigned short* __restrict__ prevb,
    const float* __restrict__ dtv,
    const float* __restrict__ Dp,
    const float* __restrict__ norm_w,
    unsigned short* __restrict__ ynu,
    float* __restrict__ ssq)
{
    int blk = blockIdx.x;
    int h = blk & 31, bc = blk >> 5;
    int c = bc & 7, b = bc >> 3;
    int tid = threadIdx.x, lane = tid & 63, wave = tid >> 6;
    __shared__ float sAc[256];
    __shared__ short Mb[256 * 64];
    __shared__ float sdi[256];   // D[h]/dt[s] for the diagonal fold
    float Dv = Dp[h];
    sAc[tid] = Acum[(long)(b * 32 + h) * 2048 + c * 256 + tid];
    sdi[tid] = Dv / dtv[(long)(b * 32 + h) * 2048 + c * 256 + tid];
    __syncthreads();
    f32x4 acc[4][4];
#pragma unroll
    for (int m = 0; m < 4; m++)
#pragma unroll
        for (int n = 0; n < 4; n++) acc[m][n] = (f32x4){0.f, 0.f, 0.f, 0.f};

    for (int zp = 0; zp < 4; ++zp) {
#pragma unroll
        for (int i = 0; i < 8; ++i) {
            int ci = i * 256 + tid;
            int s = ci >> 3, cz = ci & 7;
            int z0 = zp * 64 + cz * 8;
            short8 gv = *(const short8*)(Gm + ((long)bc * 256 + s) * 256 + z0);
            float as = sAc[s];
            short8 o;
#pragma unroll
            for (int j = 0; j < 8; ++j) {
                int z = z0 + j;
                float e = (s >= z) ? __expf(as - sAc[z]) : 0.f;
                float mval = b2f((unsigned short)gv[j]) * e;
                if (s == z) mval += sdi[s];   // D_res folded: (D/dt[s])·xdt[p][s] = D·hs[p][s]
                o[j] = (short)f2b(mval);
            }
            *(short8*)(Mb + s * 64 + (cz ^ (s & 7)) * 8) = o;
        }
        __syncthreads();
#pragma unroll
        for (int ks = 0; ks < 2; ++ks) {
            short8 af[4], bfr[4];
#pragma unroll
            for (int m = 0; m < 4; ++m) {
                int r = wave * 64 + m * 16 + (lane & 15);
                int pc = (ks * 4 + (lane >> 4)) ^ (r & 7);
                af[m] = *(const short8*)(Mb + r * 64 + pc * 8);
            }
#pragma unroll
            for (int n = 0; n < 4; ++n) {
                int p = n * 16 + (lane & 15);
                int zcol = c * 256 + zp * 64 + ks * 32 + (lane >> 4) * 8;
                bfr[n] = *(const short8*)(xdtT + (long)(h * 64 + p) * 4096 + b * 2048 + zcol);
            }
#pragma unroll
            for (int m = 0; m < 4; ++m)
#pragma unroll
                for (int n = 0; n < 4; ++n)
                    acc[m][n] = __builtin_amdgcn_mfma_f32_16x16x32_bf16(af[m], bfr[n], acc[m][n], 0, 0, 0);
        }
        __syncthreads();
    }
    // Y_off accumulate
    float el[4];
#pragma unroll
    for (int m = 0; m < 4; ++m) el[m] = __expf(sAc[wave * 64 + m * 16 + (lane & 15)]);
#pragma unroll
    for (int ks = 0; ks < 4; ++ks) {
        short8 af[4], bfr[4];
#pragma unroll
        for (int m = 0; m < 4; ++m) {
            int l = wave * 64 + m * 16 + (lane & 15);
            short8 cv = *(const short8*)(Cb + ((long)b * 2048 + c * 256 + l) * 128 + ks * 32 + (lane >> 4) * 8);
#pragma unroll
            for (int j = 0; j < 8; ++j) af[m][j] = (short)f2b(b2f((unsigned short)cv[j]) * el[m]);
        }
#pragma unroll
        for (int n = 0; n < 4; ++n) {
            int p = n * 16 + (lane & 15);
            bfr[n] = *(const short8*)(prevb + ((long)(bc * 32 + h) * 64 + p) * 128 + ks * 32 + (lane >> 4) * 8);
        }
#pragma unroll
        for (int m = 0; m < 4; ++m)
#pragma unroll
            for (int n = 0; n < 4; ++n)
                acc[m][n] = __builtin_amdgcn_mfma_f32_16x16x32_bf16(af[m], bfr[n], acc[m][n], 0, 0, 0);
    }
    // stage gate tile [64 ch][256 t] (XOR on t) into Mb's LDS
    unsigned short* gt = (unsigned short*)Mb;
#pragma unroll
    for (int i = 0; i < 8; ++i) {
        int idx = i * 256 + tid;
        int r = idx >> 5, c8 = (idx & 31) * 8;
        short8 v = *(const short8*)(projT + (long)(h * 64 + r) * 4096 + b * 2048 + c * 256 + c8);
#pragma unroll
        for (int j = 0; j < 8; ++j)
            gt[r * 256 + ((c8 + j) ^ ((r & 7) << 3))] = (unsigned short)v[j];
    }
    __syncthreads();
#pragma unroll
    for (int m = 0; m < 4; ++m)
#pragma unroll
        for (int r = 0; r < 4; ++r) {
            int tl = wave * 64 + m * 16 + ((lane >> 4) << 2) + r;
            long bt = (long)b * 2048 + c * 256 + tl;
            float part = 0.f;
#pragma unroll
            for (int n = 0; n < 4; ++n) {
                int cl = n * 16 + (lane & 15);
                int ch = h * 64 + cl;
                float yv = acc[m][n][r];
                float g = b2f(gt[cl * 256 + (tl ^ ((cl & 7) << 3))]);
                float yf = yv * g / (1.f + __expf(-g));
                part += yf * yf;
                ynu[bt * 2048 + ch] = f2b(yf * norm_w[ch]);
            }
#pragma unroll
            for (int w2 = 1; w2 < 16; w2 <<= 1) part += __shfl_xor(part, w2);
            if ((lane & 15) == 0) atomicAdd(&ssq[bt], part);
        }
}

__global__ __launch_bounds__(256) void scan_kernel(
    const float* __restrict__ states,
    const float* __restrict__ Atot,
    unsigned short* __restrict__ prevb)
{
    int bh = blockIdx.x;
    int b = bh >> 5, h = bh & 31;
    float ex[8];
#pragma unroll
    for (int c = 0; c < 8; ++c) ex[c] = __expf(Atot[bh * 8 + c]);
    for (int e = threadIdx.x; e < 8192; e += 256) {
        float S = 0.f;
#pragma unroll
        for (int c = 0; c < 8; ++c) {
            long idx = (long)((b * 8 + c) * 32 + h) * 8192 + e;
            prevb[idx] = f2b(S);
            S = ex[c] * S + states[idx];
        }
    }
}

extern "C" void kernel_launch(void* const* d_in, const int* in_sizes, int n_in,
                              void* d_out, int out_size, void* d_ws, size_t ws_size,
                              hipStream_t stream)
{
    const float* x        = (const float*)d_in[0];
    const float* in_proj  = (const float*)d_in[1];
    const float* conv_w   = (const float*)d_in[2];
    const float* conv_b   = (const float*)d_in[3];
    const float* dt_bias  = (const float*)d_in[4];
    const float* A_log    = (const float*)d_in[5];
    const float* Dp       = (const float*)d_in[6];
    const float* norm_w   = (const float*)d_in[7];
    const float* out_proj = (const float*)d_in[8];
    float* out = (float*)d_out;

    char* w = (char*)d_ws;
    auto alloc = [&](size_t bytes) { char* p = w; w += (bytes + 255) & ~(size_t)255; return p; };
    unsigned short* xb    = (unsigned short*)alloc(4096L * 1024 * 2);
    unsigned short* wb    = (unsigned short*)alloc(4384L * 1024 * 2);
    unsigned short* ob    = (unsigned short*)alloc(1024L * 2048 * 2);
    unsigned short* projT = (unsigned short*)alloc(4384L * 4096 * 2);
    float*          dtraw = (float*)        alloc(4096L * 32 * 4);
    float*          dtv   = (float*)        alloc(64L * 2048 * 4);
    float*          Acum  = (float*)        alloc(64L * 2048 * 4);
    float*          Atot  = (float*)        alloc(64L * 8 * 4);
    unsigned short* xdtT  = (unsigned short*)alloc(2048L * 4096 * 2);
    unsigned short* xdtd  = (unsigned short*)alloc(2048L * 4096 * 2);
    unsigned short* Bb    = (unsigned short*)alloc(4096L * 128 * 2);
    unsigned short* Cb    = (unsigned short*)alloc(4096L * 128 * 2);
    unsigned short* BT    = (unsigned short*)alloc(128L * 4096 * 2);
    unsigned short* Gmb   = (unsigned short*)alloc(16L * 256 * 256 * 2);
    float*          states= (float*)        alloc(2L * 8 * 2048 * 128 * 4);
    unsigned short* prevb = (unsigned short*)alloc(2L * 8 * 2048 * 128 * 2);
    unsigned short* ynu   = (unsigned short*)alloc(4096L * 2048 * 2);
    float*          ssq   = (float*)        alloc(4096L * 4);

    hipMemsetAsync(ssq, 0, 4096 * 4, stream);

    cast3_kernel<<<2048, 256, 0, stream>>>(x, xb, 4096L * 1024 / 8,
                                           in_proj, wb, 4384L * 1024 / 8,
                                           out_proj, ob, 1024L * 2048 / 8);

    // in_proj -> projT (transposed bf16) + dtraw (f32)
    gemm_nt<3><<<dim3(32 * 35, 1, 1), 256, 0, stream>>>(
        xb, 1024, 0, 0, wb, 1024, 0, 0, projT, 4096, 0, 0, dtraw, 4096, 4384, 1024, 35);

    dtcum_kernel<<<64, 256, 0, stream>>>(dtraw, dt_bias, A_log, dtv, Acum, Atot);

    convT_kernel<<<dim3(8, 36, 2), 256, 0, stream>>>(
        projT, conv_w, conv_b, dtv, Acum, Atot, xdtT, xdtd, Bb, Cb, BT);

    // Gm = C B^T per (b,c), bf16
    gemm_nt<1><<<dim3(4, 8, 2), 256, 0, stream>>>(
        Cb, 128, 256L * 128, 2048L * 128,
        Bb, 128, 256L * 128, 2048L * 128,
        Gmb, 256, 256L * 256, 8L * 256 * 256, nullptr, 256, 256, 128, 2);

    // states[hp][n] = sum_t xdtd[hp][t] BT[n][t]
    gemm_nt<0><<<dim3(16, 8, 2), 256, 0, stream>>>(
        xdtd, 4096, 256, 2048,
        BT, 4096, 256, 2048,
        states, 128, 2048L * 128, 8L * 2048 * 128, nullptr, 2048, 128, 256, 1);

    scan_kernel<<<64, 256, 0, stream>>>(states, Atot, prevb);

    ydiagoff_kernel<<<512, 256, 0, stream>>>(Gmb, Acum, xdtT, projT, Cb, prevb,
                                             dtv, Dp, norm_w, ynu, ssq);

    // out = (ynu @ ob^T) * rsqrt(ssq/2048 + eps)
    gemm_nt<4><<<dim3(32 * 8, 1, 1), 256, 0, stream>>>(
        ynu, 2048, 0, 0, ob, 2048, 0, 0, out, 1024, 0, 0, ssq, 4096, 1024, 2048, 8);
}

// Round 9
// 296.251 us; speedup vs baseline: 1.0527x; 1.0527x over previous
//
#include <hip/hip_runtime.h>
#include <stdint.h>

typedef __attribute__((ext_vector_type(8))) short short8;
typedef __attribute__((ext_vector_type(4))) float f32x4;

#define DEV static __device__ __forceinline__
#define LOG2E 1.44269504088896340736f

DEV float b2f(unsigned short u) { union { float f; unsigned int i; } x; x.i = ((unsigned int)u) << 16; return x.f; }
DEV unsigned short f2b(float f) {
    union { float f; unsigned int i; } x; x.f = f;
    unsigned int r = x.i + 0x7fffu + ((x.i >> 16) & 1u);
    return (unsigned short)(r >> 16);
}
DEV void gld_lds16(const void* g, void* l) {
    __builtin_amdgcn_global_load_lds((const __attribute__((address_space(1))) void*)g,
                                     (__attribute__((address_space(3))) void*)l, 16, 0, 0);
}
DEV int xcd_swizzle(int bid, int nwg) {
    int q = nwg >> 3, r = nwg & 7;
    int xcd = bid & 7, base = bid >> 3;
    return (xcd < r ? xcd * (q + 1) : r * (q + 1) + (xcd - r) * q) + base;
}

__global__ void cast3_kernel(const float* __restrict__ a, unsigned short* __restrict__ oa, long na8,
                             const float* __restrict__ b, unsigned short* __restrict__ ob_, long nb8,
                             const float* __restrict__ c, unsigned short* __restrict__ oc, long nc8) {
    long i = (long)blockIdx.x * blockDim.x + threadIdx.x;
    long stride = (long)gridDim.x * blockDim.x;
    long tot = na8 + nb8 + nc8;
    for (; i < tot; i += stride) {
        const float* src; unsigned short* dst; long j = i;
        if (j < na8) { src = a; dst = oa; }
        else if (j < na8 + nb8) { j -= na8; src = b; dst = ob_; }
        else { j -= na8 + nb8; src = c; dst = oc; }
        const f32x4* p = (const f32x4*)(src + j * 8);
        f32x4 v0 = p[0], v1 = p[1];
        short8 o;
        o[0] = (short)f2b(v0[0]); o[1] = (short)f2b(v0[1]); o[2] = (short)f2b(v0[2]); o[3] = (short)f2b(v0[3]);
        o[4] = (short)f2b(v1[0]); o[5] = (short)f2b(v1[1]); o[6] = (short)f2b(v1[2]); o[7] = (short)f2b(v1[3]);
        *(short8*)(dst + j * 8) = o;
    }
}

// NT GEMM, 128x128 tile, BK=64, double-buffered counted-vmcnt pipeline.
// OMODE 0: f32 C natural.  OMODE 1: bf16 C natural.
// OMODE 3: bf16 C TRANSPOSED + f32 dt cols (swizzled T tile).
// OMODE 4: f32 C natural, row-scaled by rsqrt(aux[row]/2048 + eps).
template<int OMODE>
__global__ __launch_bounds__(256) void gemm_nt(
    const unsigned short* __restrict__ A, int lda, long sAy, long sAz,
    const unsigned short* __restrict__ B, int ldb, long sBy, long sBz,
    void* __restrict__ Cp, int ldc, long sCy, long sCz,
    float* __restrict__ aux,
    int M, int N, int K, int tn)
{
    A += (long)blockIdx.y * sAy + (long)blockIdx.z * sAz;
    B += (long)blockIdx.y * sBy + (long)blockIdx.z * sBz;
    int bid = xcd_swizzle(blockIdx.x, gridDim.x);
    int im = bid / tn, in_ = bid % tn;
    int m0 = im * 128, n0 = in_ * 128;
    __shared__ short smem[2 * 2 * 128 * 64];   // 64 KB
    int tid = threadIdx.x;
    int lane = tid & 63, wave = tid >> 6;
    int wu = __builtin_amdgcn_readfirstlane(wave);
    int wm = wave >> 1, wn = wave & 1;
    f32x4 acc[4][4];
#pragma unroll
    for (int m = 0; m < 4; m++)
#pragma unroll
        for (int n = 0; n < 4; n++) acc[m][n] = (f32x4){0.f, 0.f, 0.f, 0.f};

    auto stage = [&](int k0, int s) {
        short* As = smem + s * 16384;
        short* Bs = As + 8192;
#pragma unroll
        for (int i = 0; i < 4; ++i) {
            int g = i * 256 + tid;
            int r = g >> 3, pc = g & 7;
            int cc = pc ^ (r & 7);
            gld_lds16(A + (long)(m0 + r) * lda + k0 + cc * 8, As + (i * 256 + wu * 64) * 8);
            int rb = n0 + r; rb = rb < N ? rb : N - 1;
            gld_lds16(B + (long)rb * ldb + k0 + cc * 8, Bs + (i * 256 + wu * 64) * 8);
        }
    };

    int nt = K >> 6;
    stage(0, 0);
    for (int t = 0; t < nt; ++t) {
        int cur = t & 1;
        if (t + 1 < nt) {
            stage((t + 1) << 6, cur ^ 1);
            asm volatile("s_waitcnt vmcnt(8)" ::: "memory");
        } else {
            asm volatile("s_waitcnt vmcnt(0)" ::: "memory");
        }
        __builtin_amdgcn_s_barrier();
        const short* As = smem + cur * 16384;
        const short* Bs = As + 8192;
#pragma unroll
        for (int ks = 0; ks < 2; ++ks) {
            short8 af[4], bfr[4];
#pragma unroll
            for (int m = 0; m < 4; ++m) {
                int r = wm * 64 + m * 16 + (lane & 15);
                int pc = (ks * 4 + (lane >> 4)) ^ (r & 7);
                af[m] = *(const short8*)(As + r * 64 + pc * 8);
            }
#pragma unroll
            for (int n = 0; n < 4; ++n) {
                int r = wn * 64 + n * 16 + (lane & 15);
                int pc = (ks * 4 + (lane >> 4)) ^ (r & 7);
                bfr[n] = *(const short8*)(Bs + r * 64 + pc * 8);
            }
            __builtin_amdgcn_s_setprio(1);
#pragma unroll
            for (int m = 0; m < 4; ++m)
#pragma unroll
                for (int n = 0; n < 4; ++n)
                    acc[m][n] = __builtin_amdgcn_mfma_f32_16x16x32_bf16(af[m], bfr[n], acc[m][n], 0, 0, 0);
            __builtin_amdgcn_s_setprio(0);
        }
        __builtin_amdgcn_s_barrier();
    }

    int rbase = m0 + wm * 64 + ((lane >> 4) << 2);
    int cbase = n0 + wn * 64 + (lane & 15);
    if (OMODE == 0) {
        float* C = (float*)Cp;
        C += (long)blockIdx.y * sCy + (long)blockIdx.z * sCz;
#pragma unroll
        for (int m = 0; m < 4; ++m)
#pragma unroll
            for (int n = 0; n < 4; ++n) {
                int col = cbase + n * 16;
                if (col < N) {
#pragma unroll
                    for (int r = 0; r < 4; ++r)
                        C[(long)(rbase + m * 16 + r) * ldc + col] = acc[m][n][r];
                }
            }
    } else if (OMODE == 4) {
        float* C = (float*)Cp;
#pragma unroll
        for (int m = 0; m < 4; ++m)
#pragma unroll
            for (int r = 0; r < 4; ++r) {
                int row = rbase + m * 16 + r;
                float sc = rsqrtf(aux[row] * (1.f / 2048.f) + 1e-6f);
#pragma unroll
                for (int n = 0; n < 4; ++n)
                    C[(long)row * ldc + cbase + n * 16] = acc[m][n][r] * sc;
            }
    } else if (OMODE == 1) {
        unsigned short* Cs = (unsigned short*)smem;
        int rl = wm * 64 + ((lane >> 4) << 2);
        int cl = wn * 64 + (lane & 15);
#pragma unroll
        for (int m = 0; m < 4; ++m)
#pragma unroll
            for (int r = 0; r < 4; ++r) {
                int row = rl + m * 16 + r;
                int xr = ((row >> 2) & 3) << 4;
#pragma unroll
                for (int n = 0; n < 4; ++n)
                    Cs[row * 128 + ((cl + n * 16) ^ xr)] = f2b(acc[m][n][r]);
            }
        __syncthreads();
        unsigned short* C = (unsigned short*)Cp;
        C += (long)blockIdx.y * sCy + (long)blockIdx.z * sCz;
#pragma unroll
        for (int j = 0; j < 8; ++j) {
            int chunk = j * 256 + tid;
            int row = chunk >> 4, c8 = (chunk & 15) * 8;
            int col = n0 + c8;
            int xr = ((row >> 2) & 3) << 4;
            if (col < N)
                *(short8*)(C + (long)(m0 + row) * ldc + col) = *(const short8*)(Cs + row * 128 + (c8 ^ xr));
        }
    } else { // OMODE 3
#pragma unroll
        for (int m = 0; m < 4; ++m)
#pragma unroll
            for (int n = 0; n < 4; ++n) {
                int col = cbase + n * 16;
                if (col >= 4352 && col < N) {
#pragma unroll
                    for (int r = 0; r < 4; ++r)
                        aux[(long)(rbase + m * 16 + r) * 32 + (col - 4352)] = acc[m][n][r];
                }
            }
        unsigned short* T = (unsigned short*)smem; // 128ch x 128m
        int rl = wm * 64 + ((lane >> 4) << 2);
        int cl = wn * 64 + (lane & 15);
#pragma unroll
        for (int n = 0; n < 4; ++n) {
            int ch = cl + n * 16;
            int sw = (ch & 15) << 3;
#pragma unroll
            for (int m = 0; m < 4; ++m)
#pragma unroll
                for (int r = 0; r < 4; ++r) {
                    int mrow = rl + m * 16 + r;
                    T[ch * 128 + (mrow ^ sw)] = f2b(acc[m][n][r]);
                }
        }
        __syncthreads();
        unsigned short* C = (unsigned short*)Cp;
#pragma unroll
        for (int j = 0; j < 8; ++j) {
            int idx = j * 256 + tid;
            int ch = idx >> 4, mc8 = (idx & 15) * 8;
            int gch = n0 + ch;
            if (gch < N) {
                short8 o = *(const short8*)(T + ch * 128 + (mc8 ^ ((ch & 15) << 3)));
                *(short8*)(C + (long)gch * ldc + m0 + mc8) = o;
            }
        }
    }
}

// softplus(dt)+cumsum per (b,h)
__global__ __launch_bounds__(256) void dtcum_kernel(
    const float* __restrict__ dtraw,
    const float* __restrict__ dt_bias, const float* __restrict__ A_log,
    float* __restrict__ dtv, float* __restrict__ Acum, float* __restrict__ Atot)
{
    int bh = blockIdx.x;
    int b = bh >> 5, h = bh & 31;
    int tid = threadIdx.x;
    float bias = dt_bias[h];
    float negA = -__expf(A_log[h]);
    __shared__ float s[256];
    for (int c = 0; c < 8; ++c) {
        int t = c * 256 + tid;
        float v = dtraw[(long)(b * 2048 + t) * 32 + h] + bias;
        float dt = v > 20.f ? v : log1pf(__expf(v));
        dtv[(long)bh * 2048 + t] = dt;
        s[tid] = dt * negA;
        __syncthreads();
        for (int off = 1; off < 256; off <<= 1) {
            float x = (tid >= off) ? s[tid - off] : 0.f;
            __syncthreads();
            s[tid] += x;
            __syncthreads();
        }
        Acum[(long)bh * 2048 + t] = s[tid];
        if (tid == 255) Atot[bh * 8 + c] = s[255];
        __syncthreads();
    }
}

// conv1d K=4 causal + SiLU, channel-major. grid: (8, 36, 2)
__global__ __launch_bounds__(256) void convT_kernel(
    const unsigned short* __restrict__ projT,
    const float* __restrict__ conv_w, const float* __restrict__ conv_b,
    const float* __restrict__ dtv, const float* __restrict__ Acum, const float* __restrict__ Atot,
    unsigned short* __restrict__ xdtT, unsigned short* __restrict__ xdtd,
    unsigned short* __restrict__ Bb, unsigned short* __restrict__ Cb, unsigned short* __restrict__ BT)
{
    int tt = blockIdx.x;
    int cht = blockIdx.y;
    int b = blockIdx.z;
    int t0 = tt * 256;
    int ch0 = cht * 64;
    int tid = threadIdx.x;
    __shared__ short raw[64 * 264];
    __shared__ unsigned short trsp[256 * 64];
    __shared__ float sdt[256], sac[256];
    __shared__ float satot;
    bool hidden = cht < 32;
    for (int j = 0; j < 9; ++j) {
        int idx = j * 256 + tid;
        if (idx < 64 * 33) {
            int r = idx / 33, cc = idx % 33;
            int tg = t0 - 8 + cc * 8;
            short8 v = {0, 0, 0, 0, 0, 0, 0, 0};
            if (tg >= 0)
                v = *(const short8*)(projT + (long)(2048 + ch0 + r) * 4096 + b * 2048 + tg);
            *(short8*)(raw + r * 264 + cc * 8) = v;
        }
    }
    if (hidden) {
        int h = cht;
        sdt[tid] = dtv[(long)(b * 32 + h) * 2048 + t0 + tid];
        sac[tid] = Acum[(long)(b * 32 + h) * 2048 + t0 + tid];
        if (tid == 0) satot = Atot[(b * 32 + h) * 8 + tt];
    }
    __syncthreads();
    for (int p = 0; p < 8; ++p) {
        int ch = p * 8 + (tid >> 5);
        int tb = (tid & 31) * 8;
        int cg = ch0 + ch;
        f32x4 wv = *(const f32x4*)(conv_w + cg * 4);
        float cb = conv_b[cg];
        float s[8];
#pragma unroll
        for (int j = 0; j < 8; ++j) {
            int tl = tb + j;
            float a = cb;
#pragma unroll
            for (int k = 0; k < 4; ++k)
                a += b2f((unsigned short)raw[ch * 264 + tl + 5 + k]) * wv[k];
            s[j] = a / (1.f + __expf(-a));
        }
        if (hidden) {
            short8 o1, o2;
#pragma unroll
            for (int j = 0; j < 8; ++j) {
                int tl = tb + j;
                float xdt = s[j] * sdt[tl];
                float dec = __expf(satot - sac[tl]);
                o1[j] = (short)f2b(xdt);
                o2[j] = (short)f2b(xdt * dec);
            }
            long off = (long)cg * 4096 + b * 2048 + t0 + tb;
            *(short8*)(xdtT + off) = o1;
            *(short8*)(xdtd + off) = o2;
        } else {
            short8 o;
#pragma unroll
            for (int j = 0; j < 8; ++j) o[j] = (short)f2b(s[j]);
            if (cht < 34) {
                int n = (cht - 32) * 64 + ch;
                *(short8*)(BT + (long)n * 4096 + b * 2048 + t0 + tb) = o;
            }
#pragma unroll
            for (int j = 0; j < 8; ++j) {
                int tl = tb + j;
                trsp[tl * 64 + (ch ^ ((tl & 7) << 3))] = (unsigned short)o[j];
            }
        }
    }
    if (!hidden) {
        __syncthreads();
        unsigned short* dst = (cht < 34) ? Bb : Cb;
        int n0 = ((cht - 32) & 1) * 64;
        for (int p = 0; p < 8; ++p) {
            int idx = p * 256 + tid;
            int tl = idx >> 3, c8 = (idx & 7) * 8;
            short8 o;
#pragma unroll
            for (int q = 0; q < 8; ++q)
                o[q] = (short)trsp[tl * 64 + ((c8 + q) ^ ((tl & 7) << 3))];
            *(short8*)(dst + (long)(b * 2048 + t0 + tl) * 128 + n0 + c8) = o;
        }
    }
}

// Fused Y_diag (+D on diagonal, triangular build/MFMA skip, exp2 domain)
// + Y_off + gate-SiLU + norm_w + ssq -> ynu via LDS vector stores
__global__ __launch_bounds__(256) void ydiagoff_kernel(
    const unsigned short* __restrict__ Gm,
    const float* __restrict__ Acum,
    const unsigned short* __restrict__ xdtT,
    const unsigned short* __restrict__ projT,
    const unsigned short* __restrict__ Cb,
    const unsigned short* __restrict__ prevb,
    const float* __restrict__ dtv,
    const float* __restrict__ Dp,
    const float* __restrict__ norm_w,
    unsigned short* __restrict__ ynu,
    float* __restrict__ ssq)
{
    int blk = blockIdx.x;
    int h = blk & 31, bc = blk >> 5;
    int c = bc & 7, b = bc >> 3;
    int tid = threadIdx.x, lane = tid & 63, wave = tid >> 6;
    __shared__ float sAc[256];           // Acum * log2(e)
    __shared__ short Mb[256 * 64];       // M tile (reused as gate tile later)
    __shared__ float sdi[256];           // D/dt diagonal fold
    __shared__ float snw[64];            // norm_w slice
    __shared__ unsigned short yt[256 * 72]; // output staging (pad 72)
    float Dv = Dp[h];
    sAc[tid] = Acum[(long)(b * 32 + h) * 2048 + c * 256 + tid] * LOG2E;
    sdi[tid] = Dv / dtv[(long)(b * 32 + h) * 2048 + c * 256 + tid];
    if (tid < 64) snw[tid] = norm_w[h * 64 + tid];
    __syncthreads();
    f32x4 acc[4][4];
#pragma unroll
    for (int m = 0; m < 4; m++)
#pragma unroll
        for (int n = 0; n < 4; n++) acc[m][n] = (f32x4){0.f, 0.f, 0.f, 0.f};

#pragma unroll
    for (int zp = 0; zp < 4; ++zp) {
        const int z0 = zp * 64;
        const int niter = 8 - zp * 2;   // rows s in [z0,256): (256-z0)*8/256 iterations
        for (int i = 0; i < niter; ++i) {
            int ci = i * 256 + tid;
            int s = z0 + (ci >> 3), cz = ci & 7;
            int zc0 = z0 + cz * 8;
            short8 gv = *(const short8*)(Gm + ((long)bc * 256 + s) * 256 + zc0);
            float as = sAc[s];
            short8 o;
#pragma unroll
            for (int j = 0; j < 8; ++j) {
                int z = zc0 + j;
                float e = (s >= z) ? exp2f(as - sAc[z]) : 0.f;
                float mval = b2f((unsigned short)gv[j]) * e;
                if (s == z) mval += sdi[s];
                o[j] = (short)f2b(mval);
            }
            *(short8*)(Mb + s * 64 + (cz ^ (s & 7)) * 8) = o;
        }
        __syncthreads();
#pragma unroll
        for (int ks = 0; ks < 2; ++ks) {
            short8 af[4], bfr[4];
#pragma unroll
            for (int m = 0; m < 4; ++m) {
                if (wave * 64 + m * 16 >= z0) {
                    int r = wave * 64 + m * 16 + (lane & 15);
                    int pc = (ks * 4 + (lane >> 4)) ^ (r & 7);
                    af[m] = *(const short8*)(Mb + r * 64 + pc * 8);
                }
            }
#pragma unroll
            for (int n = 0; n < 4; ++n) {
                int p = n * 16 + (lane & 15);
                int zcol = c * 256 + z0 + ks * 32 + (lane >> 4) * 8;
                bfr[n] = *(const short8*)(xdtT + (long)(h * 64 + p) * 4096 + b * 2048 + zcol);
            }
#pragma unroll
            for (int m = 0; m < 4; ++m) {
                if (wave * 64 + m * 16 >= z0) {
#pragma unroll
                    for (int n = 0; n < 4; ++n)
                        acc[m][n] = __builtin_amdgcn_mfma_f32_16x16x32_bf16(af[m], bfr[n], acc[m][n], 0, 0, 0);
                }
            }
        }
        __syncthreads();
    }
    // Y_off accumulate (exp(Acum[l]) = exp2(sAc[l]))
    float el[4];
#pragma unroll
    for (int m = 0; m < 4; ++m) el[m] = exp2f(sAc[wave * 64 + m * 16 + (lane & 15)]);
#pragma unroll
    for (int ks = 0; ks < 4; ++ks) {
        short8 af[4], bfr[4];
#pragma unroll
        for (int m = 0; m < 4; ++m) {
            int l = wave * 64 + m * 16 + (lane & 15);
            short8 cv = *(const short8*)(Cb + ((long)b * 2048 + c * 256 + l) * 128 + ks * 32 + (lane >> 4) * 8);
#pragma unroll
            for (int j = 0; j < 8; ++j) af[m][j] = (short)f2b(b2f((unsigned short)cv[j]) * el[m]);
        }
#pragma unroll
        for (int n = 0; n < 4; ++n) {
            int p = n * 16 + (lane & 15);
            bfr[n] = *(const short8*)(prevb + ((long)(bc * 32 + h) * 64 + p) * 128 + ks * 32 + (lane >> 4) * 8);
        }
#pragma unroll
        for (int m = 0; m < 4; ++m)
#pragma unroll
            for (int n = 0; n < 4; ++n)
                acc[m][n] = __builtin_amdgcn_mfma_f32_16x16x32_bf16(af[m], bfr[n], acc[m][n], 0, 0, 0);
    }
    // stage gate tile [64 ch][256 t] (XOR on t) into Mb's LDS
    unsigned short* gt = (unsigned short*)Mb;
#pragma unroll
    for (int i = 0; i < 8; ++i) {
        int idx = i * 256 + tid;
        int r = idx >> 5, c8 = (idx & 31) * 8;
        short8 v = *(const short8*)(projT + (long)(h * 64 + r) * 4096 + b * 2048 + c * 256 + c8);
#pragma unroll
        for (int j = 0; j < 8; ++j)
            gt[r * 256 + ((c8 + j) ^ ((r & 7) << 3))] = (unsigned short)v[j];
    }
    __syncthreads();
#pragma unroll
    for (int m = 0; m < 4; ++m)
#pragma unroll
        for (int r = 0; r < 4; ++r) {
            int tl = wave * 64 + m * 16 + ((lane >> 4) << 2) + r;
            long bt = (long)b * 2048 + c * 256 + tl;
            float part = 0.f;
#pragma unroll
            for (int n = 0; n < 4; ++n) {
                int cl = n * 16 + (lane & 15);
                float yv = acc[m][n][r];
                float g = b2f(gt[cl * 256 + (tl ^ ((cl & 7) << 3))]);
                float yf = yv * g / (1.f + __expf(-g));
                part += yf * yf;
                yt[tl * 72 + cl] = f2b(yf * snw[cl]);
            }
#pragma unroll
            for (int w2 = 1; w2 < 16; w2 <<= 1) part += __shfl_xor(part, w2);
            if ((lane & 15) == 0) atomicAdd(&ssq[bt], part);
        }
    __syncthreads();
    // vectorized ynu stores
#pragma unroll
    for (int j = 0; j < 8; ++j) {
        int idx = j * 256 + tid;
        int tl = idx >> 3, c8 = (idx & 7) * 8;
        short8 o = *(const short8*)(yt + tl * 72 + c8);
        *(short8*)(ynu + ((long)b * 2048 + c * 256 + tl) * 2048 + h * 64 + c8) = o;
    }
}

__global__ __launch_bounds__(256) void scan_kernel(
    const float* __restrict__ states,
    const float* __restrict__ Atot,
    unsigned short* __restrict__ prevb)
{
    int bh = blockIdx.x;
    int b = bh >> 5, h = bh & 31;
    float ex[8];
#pragma unroll
    for (int c = 0; c < 8; ++c) ex[c] = __expf(Atot[bh * 8 + c]);
    for (int e = threadIdx.x; e < 8192; e += 256) {
        float S = 0.f;
#pragma unroll
        for (int c = 0; c < 8; ++c) {
            long idx = (long)((b * 8 + c) * 32 + h) * 8192 + e;
            prevb[idx] = f2b(S);
            S = ex[c] * S + states[idx];
        }
    }
}

extern "C" void kernel_launch(void* const* d_in, const int* in_sizes, int n_in,
                              void* d_out, int out_size, void* d_ws, size_t ws_size,
                              hipStream_t stream)
{
    const float* x        = (const float*)d_in[0];
    const float* in_proj  = (const float*)d_in[1];
    const float* conv_w   = (const float*)d_in[2];
    const float* conv_b   = (const float*)d_in[3];
    const float* dt_bias  = (const float*)d_in[4];
    const float* A_log    = (const float*)d_in[5];
    const float* Dp       = (const float*)d_in[6];
    const float* norm_w   = (const float*)d_in[7];
    const float* out_proj = (const float*)d_in[8];
    float* out = (float*)d_out;

    char* w = (char*)d_ws;
    auto alloc = [&](size_t bytes) { char* p = w; w += (bytes + 255) & ~(size_t)255; return p; };
    unsigned short* xb    = (unsigned short*)alloc(4096L * 1024 * 2);
    unsigned short* wb    = (unsigned short*)alloc(4384L * 1024 * 2);
    unsigned short* ob    = (unsigned short*)alloc(1024L * 2048 * 2);
    unsigned short* projT = (unsigned short*)alloc(4384L * 4096 * 2);
    float*          dtraw = (float*)        alloc(4096L * 32 * 4);
    float*          dtv   = (float*)        alloc(64L * 2048 * 4);
    float*          Acum  = (float*)        alloc(64L * 2048 * 4);
    float*          Atot  = (float*)        alloc(64L * 8 * 4);
    unsigned short* xdtT  = (unsigned short*)alloc(2048L * 4096 * 2);
    unsigned short* xdtd  = (unsigned short*)alloc(2048L * 4096 * 2);
    unsigned short* Bb    = (unsigned short*)alloc(4096L * 128 * 2);
    unsigned short* Cb    = (unsigned short*)alloc(4096L * 128 * 2);
    unsigned short* BT    = (unsigned short*)alloc(128L * 4096 * 2);
    unsigned short* Gmb   = (unsigned short*)alloc(16L * 256 * 256 * 2);
    float*          states= (float*)        alloc(2L * 8 * 2048 * 128 * 4);
    unsigned short* prevb = (unsigned short*)alloc(2L * 8 * 2048 * 128 * 2);
    unsigned short* ynu   = (unsigned short*)alloc(4096L * 2048 * 2);
    float*          ssq   = (float*)        alloc(4096L * 4);

    hipMemsetAsync(ssq, 0, 4096 * 4, stream);

    cast3_kernel<<<2048, 256, 0, stream>>>(x, xb, 4096L * 1024 / 8,
                                           in_proj, wb, 4384L * 1024 / 8,
                                           out_proj, ob, 1024L * 2048 / 8);

    gemm_nt<3><<<dim3(32 * 35, 1, 1), 256, 0, stream>>>(
        xb, 1024, 0, 0, wb, 1024, 0, 0, projT, 4096, 0, 0, dtraw, 4096, 4384, 1024, 35);

    dtcum_kernel<<<64, 256, 0, stream>>>(dtraw, dt_bias, A_log, dtv, Acum, Atot);

    convT_kernel<<<dim3(8, 36, 2), 256, 0, stream>>>(
        projT, conv_w, conv_b, dtv, Acum, Atot, xdtT, xdtd, Bb, Cb, BT);

    gemm_nt<1><<<dim3(4, 8, 2), 256, 0, stream>>>(
        Cb, 128, 256L * 128, 2048L * 128,
        Bb, 128, 256L * 128, 2048L * 128,
        Gmb, 256, 256L * 256, 8L * 256 * 256, nullptr, 256, 256, 128, 2);

    gemm_nt<0><<<dim3(16, 8, 2), 256, 0, stream>>>(
        xdtd, 4096, 256, 2048,
        BT, 4096, 256, 2048,
        states, 128, 2048L * 128, 8L * 2048 * 128, nullptr, 2048, 128, 256, 1);

    scan_kernel<<<64, 256, 0, stream>>>(states, Atot, prevb);

    ydiagoff_kernel<<<512, 256, 0, stream>>>(Gmb, Acum, xdtT, projT, Cb, prevb,
                                             dtv, Dp, norm_w, ynu, ssq);

    gemm_nt<4><<<dim3(32 * 8, 1, 1), 256, 0, stream>>>(
        ynu, 2048, 0, 0, ob, 2048, 0, 0, out, 1024, 0, 0, ssq, 4096, 1024, 2048, 8);
}

// Round 10
// 273.381 us; speedup vs baseline: 1.1408x; 1.0837x over previous
//
#include <hip/hip_runtime.h>
#include <stdint.h>

typedef __attribute__((ext_vector_type(8))) short short8;
typedef __attribute__((ext_vector_type(4))) float f32x4;

#define DEV static __device__ __forceinline__
#define LOG2E 1.44269504088896340736f

DEV float b2f(unsigned short u) { union { float f; unsigned int i; } x; x.i = ((unsigned int)u) << 16; return x.f; }
DEV unsigned short f2b(float f) {
    union { float f; unsigned int i; } x; x.f = f;
    unsigned int r = x.i + 0x7fffu + ((x.i >> 16) & 1u);
    return (unsigned short)(r >> 16);
}
DEV void gld_lds16(const void* g, void* l) {
    __builtin_amdgcn_global_load_lds((const __attribute__((address_space(1))) void*)g,
                                     (__attribute__((address_space(3))) void*)l, 16, 0, 0);
}

__global__ void cast3_kernel(const float* __restrict__ a, unsigned short* __restrict__ oa, long na8,
                             const float* __restrict__ b, unsigned short* __restrict__ ob_, long nb8,
                             const float* __restrict__ c, unsigned short* __restrict__ oc, long nc8) {
    long i = (long)blockIdx.x * blockDim.x + threadIdx.x;
    long stride = (long)gridDim.x * blockDim.x;
    long tot = na8 + nb8 + nc8;
    for (; i < tot; i += stride) {
        const float* src; unsigned short* dst; long j = i;
        if (j < na8) { src = a; dst = oa; }
        else if (j < na8 + nb8) { j -= na8; src = b; dst = ob_; }
        else { j -= na8 + nb8; src = c; dst = oc; }
        const f32x4* p = (const f32x4*)(src + j * 8);
        f32x4 v0 = p[0], v1 = p[1];
        short8 o;
        o[0] = (short)f2b(v0[0]); o[1] = (short)f2b(v0[1]); o[2] = (short)f2b(v0[2]); o[3] = (short)f2b(v0[3]);
        o[4] = (short)f2b(v1[0]); o[5] = (short)f2b(v1[1]); o[6] = (short)f2b(v1[2]); o[7] = (short)f2b(v1[3]);
        *(short8*)(dst + j * 8) = o;
    }
}

// NT GEMM, 128x128 tile, BK=64, double-buffered counted-vmcnt pipeline.
// 2D XCD partition (gr x 8/gr rectangle per XCD, im-fastest) when gr>0:
// per-XCD working set ~2MB A + ~4.5MB B -> L2-resident, kills cross-XCD B dup.
// OMODE 0: f32 C.  OMODE 1: bf16 C.  OMODE 3: bf16 C transposed + f32 dt cols.
// OMODE 4: f32 C row-scaled by rsqrt(aux[row]/2048+eps).
template<int OMODE>
__global__ __launch_bounds__(256) void gemm_nt(
    const unsigned short* __restrict__ A, int lda, long sAy, long sAz,
    const unsigned short* __restrict__ B, int ldb, long sBy, long sBz,
    void* __restrict__ Cp, int ldc, long sCy, long sCz,
    float* __restrict__ aux,
    int M, int N, int K, int tm, int tn, int gr)
{
    int im, in_;
    if (gr > 0) {
        int gc = 8 / gr;
        int rows_per = (tm + gr - 1) / gr;
        int cols_per = (tn + gc - 1) / gc;
        int xcd = blockIdx.x & 7, idx = blockIdx.x >> 3;
        im = (xcd / gc) * rows_per + idx % rows_per;
        in_ = (xcd % gc) * cols_per + idx / rows_per;
        if (im >= tm || in_ >= tn) return;
    } else {
        im = blockIdx.x / tn; in_ = blockIdx.x % tn;
    }
    A += (long)blockIdx.y * sAy + (long)blockIdx.z * sAz;
    B += (long)blockIdx.y * sBy + (long)blockIdx.z * sBz;
    int m0 = im * 128, n0 = in_ * 128;
    __shared__ short smem[2 * 2 * 128 * 64];   // 64 KB
    int tid = threadIdx.x;
    int lane = tid & 63, wave = tid >> 6;
    int wu = __builtin_amdgcn_readfirstlane(wave);
    int wm = wave >> 1, wn = wave & 1;
    f32x4 acc[4][4];
#pragma unroll
    for (int m = 0; m < 4; m++)
#pragma unroll
        for (int n = 0; n < 4; n++) acc[m][n] = (f32x4){0.f, 0.f, 0.f, 0.f};

    auto stage = [&](int k0, int s) {
        short* As = smem + s * 16384;
        short* Bs = As + 8192;
#pragma unroll
        for (int i = 0; i < 4; ++i) {
            int g = i * 256 + tid;
            int r = g >> 3, pc = g & 7;
            int cc = pc ^ (r & 7);
            gld_lds16(A + (long)(m0 + r) * lda + k0 + cc * 8, As + (i * 256 + wu * 64) * 8);
            int rb = n0 + r; rb = rb < N ? rb : N - 1;
            gld_lds16(B + (long)rb * ldb + k0 + cc * 8, Bs + (i * 256 + wu * 64) * 8);
        }
    };

    int nt = K >> 6;
    stage(0, 0);
    for (int t = 0; t < nt; ++t) {
        int cur = t & 1;
        if (t + 1 < nt) {
            stage((t + 1) << 6, cur ^ 1);
            asm volatile("s_waitcnt vmcnt(8)" ::: "memory");
        } else {
            asm volatile("s_waitcnt vmcnt(0)" ::: "memory");
        }
        __builtin_amdgcn_s_barrier();
        const short* As = smem + cur * 16384;
        const short* Bs = As + 8192;
#pragma unroll
        for (int ks = 0; ks < 2; ++ks) {
            short8 af[4], bfr[4];
#pragma unroll
            for (int m = 0; m < 4; ++m) {
                int r = wm * 64 + m * 16 + (lane & 15);
                int pc = (ks * 4 + (lane >> 4)) ^ (r & 7);
                af[m] = *(const short8*)(As + r * 64 + pc * 8);
            }
#pragma unroll
            for (int n = 0; n < 4; ++n) {
                int r = wn * 64 + n * 16 + (lane & 15);
                int pc = (ks * 4 + (lane >> 4)) ^ (r & 7);
                bfr[n] = *(const short8*)(Bs + r * 64 + pc * 8);
            }
            __builtin_amdgcn_s_setprio(1);
#pragma unroll
            for (int m = 0; m < 4; ++m)
#pragma unroll
                for (int n = 0; n < 4; ++n)
                    acc[m][n] = __builtin_amdgcn_mfma_f32_16x16x32_bf16(af[m], bfr[n], acc[m][n], 0, 0, 0);
            __builtin_amdgcn_s_setprio(0);
        }
        __builtin_amdgcn_s_barrier();
    }

    int rbase = m0 + wm * 64 + ((lane >> 4) << 2);
    int cbase = n0 + wn * 64 + (lane & 15);
    if (OMODE == 0) {
        float* C = (float*)Cp;
        C += (long)blockIdx.y * sCy + (long)blockIdx.z * sCz;
#pragma unroll
        for (int m = 0; m < 4; ++m)
#pragma unroll
            for (int n = 0; n < 4; ++n) {
                int col = cbase + n * 16;
                if (col < N) {
#pragma unroll
                    for (int r = 0; r < 4; ++r)
                        C[(long)(rbase + m * 16 + r) * ldc + col] = acc[m][n][r];
                }
            }
    } else if (OMODE == 4) {
        float* C = (float*)Cp;
#pragma unroll
        for (int m = 0; m < 4; ++m)
#pragma unroll
            for (int r = 0; r < 4; ++r) {
                int row = rbase + m * 16 + r;
                float sc = rsqrtf(aux[row] * (1.f / 2048.f) + 1e-6f);
#pragma unroll
                for (int n = 0; n < 4; ++n)
                    C[(long)row * ldc + cbase + n * 16] = acc[m][n][r] * sc;
            }
    } else if (OMODE == 1) {
        unsigned short* Cs = (unsigned short*)smem;
        int rl = wm * 64 + ((lane >> 4) << 2);
        int cl = wn * 64 + (lane & 15);
#pragma unroll
        for (int m = 0; m < 4; ++m)
#pragma unroll
            for (int r = 0; r < 4; ++r) {
                int row = rl + m * 16 + r;
                int xr = ((row >> 2) & 3) << 4;
#pragma unroll
                for (int n = 0; n < 4; ++n)
                    Cs[row * 128 + ((cl + n * 16) ^ xr)] = f2b(acc[m][n][r]);
            }
        __syncthreads();
        unsigned short* C = (unsigned short*)Cp;
        C += (long)blockIdx.y * sCy + (long)blockIdx.z * sCz;
#pragma unroll
        for (int j = 0; j < 8; ++j) {
            int chunk = j * 256 + tid;
            int row = chunk >> 4, c8 = (chunk & 15) * 8;
            int col = n0 + c8;
            int xr = ((row >> 2) & 3) << 4;
            if (col < N)
                *(short8*)(C + (long)(m0 + row) * ldc + col) = *(const short8*)(Cs + row * 128 + (c8 ^ xr));
        }
    } else { // OMODE 3
#pragma unroll
        for (int m = 0; m < 4; ++m)
#pragma unroll
            for (int n = 0; n < 4; ++n) {
                int col = cbase + n * 16;
                if (col >= 4352 && col < N) {
#pragma unroll
                    for (int r = 0; r < 4; ++r)
                        aux[(long)(rbase + m * 16 + r) * 32 + (col - 4352)] = acc[m][n][r];
                }
            }
        unsigned short* T = (unsigned short*)smem; // 128ch x 128m
        int rl = wm * 64 + ((lane >> 4) << 2);
        int cl = wn * 64 + (lane & 15);
#pragma unroll
        for (int n = 0; n < 4; ++n) {
            int ch = cl + n * 16;
            int sw = (ch & 15) << 3;
#pragma unroll
            for (int m = 0; m < 4; ++m)
#pragma unroll
                for (int r = 0; r < 4; ++r) {
                    int mrow = rl + m * 16 + r;
                    T[ch * 128 + (mrow ^ sw)] = f2b(acc[m][n][r]);
                }
        }
        __syncthreads();
        unsigned short* C = (unsigned short*)Cp;
#pragma unroll
        for (int j = 0; j < 8; ++j) {
            int idx = j * 256 + tid;
            int ch = idx >> 4, mc8 = (idx & 15) * 8;
            int gch = n0 + ch;
            if (gch < N) {
                short8 o = *(const short8*)(T + ch * 128 + (mc8 ^ ((ch & 15) << 3)));
                *(short8*)(C + (long)gch * ldc + m0 + mc8) = o;
            }
        }
    }
}

// softplus(dt)+cumsum, one block per (b,h,chunk) — chunks are independent
__global__ __launch_bounds__(256) void dtcum_kernel(
    const float* __restrict__ dtraw,
    const float* __restrict__ dt_bias, const float* __restrict__ A_log,
    float* __restrict__ dtv, float* __restrict__ Acum, float* __restrict__ Atot)
{
    int blk = blockIdx.x;            // (b*32+h)*8 + c
    int c = blk & 7, bh = blk >> 3;
    int b = bh >> 5, h = bh & 31;
    int tid = threadIdx.x;
    float bias = dt_bias[h];
    float negA = -__expf(A_log[h]);
    __shared__ float s[256];
    int t = c * 256 + tid;
    float v = dtraw[(long)(b * 2048 + t) * 32 + h] + bias;
    float dt = v > 20.f ? v : log1pf(__expf(v));
    dtv[(long)bh * 2048 + t] = dt;
    s[tid] = dt * negA;
    __syncthreads();
    for (int off = 1; off < 256; off <<= 1) {
        float x = (tid >= off) ? s[tid - off] : 0.f;
        __syncthreads();
        s[tid] += x;
        __syncthreads();
    }
    Acum[(long)bh * 2048 + t] = s[tid];
    if (tid == 255) Atot[bh * 8 + c] = s[255];
}

// conv1d K=4 causal + SiLU, channel-major. grid: (8, 36, 2)
__global__ __launch_bounds__(256) void convT_kernel(
    const unsigned short* __restrict__ projT,
    const float* __restrict__ conv_w, const float* __restrict__ conv_b,
    const float* __restrict__ dtv, const float* __restrict__ Acum, const float* __restrict__ Atot,
    unsigned short* __restrict__ xdtT, unsigned short* __restrict__ xdtd,
    unsigned short* __restrict__ Bb, unsigned short* __restrict__ Cb, unsigned short* __restrict__ BT)
{
    int tt = blockIdx.x;
    int cht = blockIdx.y;
    int b = blockIdx.z;
    int t0 = tt * 256;
    int ch0 = cht * 64;
    int tid = threadIdx.x;
    __shared__ short raw[64 * 264];
    __shared__ unsigned short trsp[256 * 64];
    __shared__ float sdt[256], sac[256];
    __shared__ float satot;
    bool hidden = cht < 32;
    for (int j = 0; j < 9; ++j) {
        int idx = j * 256 + tid;
        if (idx < 64 * 33) {
            int r = idx / 33, cc = idx % 33;
            int tg = t0 - 8 + cc * 8;
            short8 v = {0, 0, 0, 0, 0, 0, 0, 0};
            if (tg >= 0)
                v = *(const short8*)(projT + (long)(2048 + ch0 + r) * 4096 + b * 2048 + tg);
            *(short8*)(raw + r * 264 + cc * 8) = v;
        }
    }
    if (hidden) {
        int h = cht;
        sdt[tid] = dtv[(long)(b * 32 + h) * 2048 + t0 + tid];
        sac[tid] = Acum[(long)(b * 32 + h) * 2048 + t0 + tid];
        if (tid == 0) satot = Atot[(b * 32 + h) * 8 + tt];
    }
    __syncthreads();
    for (int p = 0; p < 8; ++p) {
        int ch = p * 8 + (tid >> 5);
        int tb = (tid & 31) * 8;
        int cg = ch0 + ch;
        f32x4 wv = *(const f32x4*)(conv_w + cg * 4);
        float cb = conv_b[cg];
        float s[8];
#pragma unroll
        for (int j = 0; j < 8; ++j) {
            int tl = tb + j;
            float a = cb;
#pragma unroll
            for (int k = 0; k < 4; ++k)
                a += b2f((unsigned short)raw[ch * 264 + tl + 5 + k]) * wv[k];
            s[j] = a / (1.f + __expf(-a));
        }
        if (hidden) {
            short8 o1, o2;
#pragma unroll
            for (int j = 0; j < 8; ++j) {
                int tl = tb + j;
                float xdt = s[j] * sdt[tl];
                float dec = __expf(satot - sac[tl]);
                o1[j] = (short)f2b(xdt);
                o2[j] = (short)f2b(xdt * dec);
            }
            long off = (long)cg * 4096 + b * 2048 + t0 + tb;
            *(short8*)(xdtT + off) = o1;
            *(short8*)(xdtd + off) = o2;
        } else {
            short8 o;
#pragma unroll
            for (int j = 0; j < 8; ++j) o[j] = (short)f2b(s[j]);
            if (cht < 34) {
                int n = (cht - 32) * 64 + ch;
                *(short8*)(BT + (long)n * 4096 + b * 2048 + t0 + tb) = o;
            }
#pragma unroll
            for (int j = 0; j < 8; ++j) {
                int tl = tb + j;
                trsp[tl * 64 + (ch ^ ((tl & 7) << 3))] = (unsigned short)o[j];
            }
        }
    }
    if (!hidden) {
        __syncthreads();
        unsigned short* dst = (cht < 34) ? Bb : Cb;
        int n0 = ((cht - 32) & 1) * 64;
        for (int p = 0; p < 8; ++p) {
            int idx = p * 256 + tid;
            int tl = idx >> 3, c8 = (idx & 7) * 8;
            short8 o;
#pragma unroll
            for (int q = 0; q < 8; ++q)
                o[q] = (short)trsp[tl * 64 + ((c8 + q) ^ ((tl & 7) << 3))];
            *(short8*)(dst + (long)(b * 2048 + t0 + tl) * 128 + n0 + c8) = o;
        }
    }
}

// Fused Y_diag (+D diag, triangular skip, exp2) + Y_off + gate + norm_w + ssq -> ynu
__global__ __launch_bounds__(256) void ydiagoff_kernel(
    const unsigned short* __restrict__ Gm,
    const float* __restrict__ Acum,
    const unsigned short* __restrict__ xdtT,
    const unsigned short* __restrict__ projT,
    const unsigned short* __restrict__ Cb,
    const unsigned short* __restrict__ prevb,
    const float* __restrict__ dtv,
    const float* __restrict__ Dp,
    const float* __restrict__ norm_w,
    unsigned short* __restrict__ ynu,
    float* __restrict__ ssq)
{
    int blk = blockIdx.x;
    int h = blk & 31, bc = blk >> 5;
    int c = bc & 7, b = bc >> 3;
    int tid = threadIdx.x, lane = tid & 63, wave = tid >> 6;
    __shared__ float sAc[256];
    __shared__ short Mb[256 * 64];
    __shared__ float sdi[256];
    __shared__ float snw[64];
    __shared__ unsigned short yt[256 * 72];
    float Dv = Dp[h];
    sAc[tid] = Acum[(long)(b * 32 + h) * 2048 + c * 256 + tid] * LOG2E;
    sdi[tid] = Dv / dtv[(long)(b * 32 + h) * 2048 + c * 256 + tid];
    if (tid < 64) snw[tid] = norm_w[h * 64 + tid];
    __syncthreads();
    f32x4 acc[4][4];
#pragma unroll
    for (int m = 0; m < 4; m++)
#pragma unroll
        for (int n = 0; n < 4; n++) acc[m][n] = (f32x4){0.f, 0.f, 0.f, 0.f};

#pragma unroll
    for (int zp = 0; zp < 4; ++zp) {
        const int z0 = zp * 64;
        const int niter = 8 - zp * 2;
        for (int i = 0; i < niter; ++i) {
            int ci = i * 256 + tid;
            int s = z0 + (ci >> 3), cz = ci & 7;
            int zc0 = z0 + cz * 8;
            short8 gv = *(const short8*)(Gm + ((long)bc * 256 + s) * 256 + zc0);
            float as = sAc[s];
            short8 o;
#pragma unroll
            for (int j = 0; j < 8; ++j) {
                int z = zc0 + j;
                float e = (s >= z) ? exp2f(as - sAc[z]) : 0.f;
                float mval = b2f((unsigned short)gv[j]) * e;
                if (s == z) mval += sdi[s];
                o[j] = (short)f2b(mval);
            }
            *(short8*)(Mb + s * 64 + (cz ^ (s & 7)) * 8) = o;
        }
        __syncthreads();
#pragma unroll
        for (int ks = 0; ks < 2; ++ks) {
            short8 af[4], bfr[4];
#pragma unroll
            for (int m = 0; m < 4; ++m) {
                if (wave * 64 + m * 16 >= z0) {
                    int r = wave * 64 + m * 16 + (lane & 15);
                    int pc = (ks * 4 + (lane >> 4)) ^ (r & 7);
                    af[m] = *(const short8*)(Mb + r * 64 + pc * 8);
                }
            }
#pragma unroll
            for (int n = 0; n < 4; ++n) {
                int p = n * 16 + (lane & 15);
                int zcol = c * 256 + z0 + ks * 32 + (lane >> 4) * 8;
                bfr[n] = *(const short8*)(xdtT + (long)(h * 64 + p) * 4096 + b * 2048 + zcol);
            }
#pragma unroll
            for (int m = 0; m < 4; ++m) {
                if (wave * 64 + m * 16 >= z0) {
#pragma unroll
                    for (int n = 0; n < 4; ++n)
                        acc[m][n] = __builtin_amdgcn_mfma_f32_16x16x32_bf16(af[m], bfr[n], acc[m][n], 0, 0, 0);
                }
            }
        }
        __syncthreads();
    }
    float el[4];
#pragma unroll
    for (int m = 0; m < 4; ++m) el[m] = exp2f(sAc[wave * 64 + m * 16 + (lane & 15)]);
#pragma unroll
    for (int ks = 0; ks < 4; ++ks) {
        short8 af[4], bfr[4];
#pragma unroll
        for (int m = 0; m < 4; ++m) {
            int l = wave * 64 + m * 16 + (lane & 15);
            short8 cv = *(const short8*)(Cb + ((long)b * 2048 + c * 256 + l) * 128 + ks * 32 + (lane >> 4) * 8);
#pragma unroll
            for (int j = 0; j < 8; ++j) af[m][j] = (short)f2b(b2f((unsigned short)cv[j]) * el[m]);
        }
#pragma unroll
        for (int n = 0; n < 4; ++n) {
            int p = n * 16 + (lane & 15);
            bfr[n] = *(const short8*)(prevb + ((long)(bc * 32 + h) * 64 + p) * 128 + ks * 32 + (lane >> 4) * 8);
        }
#pragma unroll
        for (int m = 0; m < 4; ++m)
#pragma unroll
            for (int n = 0; n < 4; ++n)
                acc[m][n] = __builtin_amdgcn_mfma_f32_16x16x32_bf16(af[m], bfr[n], acc[m][n], 0, 0, 0);
    }
    unsigned short* gt = (unsigned short*)Mb;
#pragma unroll
    for (int i = 0; i < 8; ++i) {
        int idx = i * 256 + tid;
        int r = idx >> 5, c8 = (idx & 31) * 8;
        short8 v = *(const short8*)(projT + (long)(h * 64 + r) * 4096 + b * 2048 + c * 256 + c8);
#pragma unroll
        for (int j = 0; j < 8; ++j)
            gt[r * 256 + ((c8 + j) ^ ((r & 7) << 3))] = (unsigned short)v[j];
    }
    __syncthreads();
#pragma unroll
    for (int m = 0; m < 4; ++m)
#pragma unroll
        for (int r = 0; r < 4; ++r) {
            int tl = wave * 64 + m * 16 + ((lane >> 4) << 2) + r;
            long bt = (long)b * 2048 + c * 256 + tl;
            float part = 0.f;
#pragma unroll
            for (int n = 0; n < 4; ++n) {
                int cl = n * 16 + (lane & 15);
                float yv = acc[m][n][r];
                float g = b2f(gt[cl * 256 + (tl ^ ((cl & 7) << 3))]);
                float yf = yv * g / (1.f + __expf(-g));
                part += yf * yf;
                yt[tl * 72 + cl] = f2b(yf * snw[cl]);
            }
#pragma unroll
            for (int w2 = 1; w2 < 16; w2 <<= 1) part += __shfl_xor(part, w2);
            if ((lane & 15) == 0) atomicAdd(&ssq[bt], part);
        }
    __syncthreads();
#pragma unroll
    for (int j = 0; j < 8; ++j) {
        int idx = j * 256 + tid;
        int tl = idx >> 3, c8 = (idx & 7) * 8;
        short8 o = *(const short8*)(yt + tl * 72 + c8);
        *(short8*)(ynu + ((long)b * 2048 + c * 256 + tl) * 2048 + h * 64 + c8) = o;
    }
}

// inter-chunk scan, e-sliced: grid 512 = 64 bh x 8 slices
__global__ __launch_bounds__(256) void scan_kernel(
    const float* __restrict__ states,
    const float* __restrict__ Atot,
    unsigned short* __restrict__ prevb)
{
    int blk = blockIdx.x;
    int bh = blk >> 3, slice = blk & 7;
    int b = bh >> 5, h = bh & 31;
    float ex[8];
#pragma unroll
    for (int c = 0; c < 8; ++c) ex[c] = __expf(Atot[bh * 8 + c]);
    int e0 = slice * 1024;
    for (int e = e0 + threadIdx.x; e < e0 + 1024; e += 256) {
        float S = 0.f;
#pragma unroll
        for (int c = 0; c < 8; ++c) {
            long idx = (long)((b * 8 + c) * 32 + h) * 8192 + e;
            prevb[idx] = f2b(S);
            S = ex[c] * S + states[idx];
        }
    }
}

extern "C" void kernel_launch(void* const* d_in, const int* in_sizes, int n_in,
                              void* d_out, int out_size, void* d_ws, size_t ws_size,
                              hipStream_t stream)
{
    const float* x        = (const float*)d_in[0];
    const float* in_proj  = (const float*)d_in[1];
    const float* conv_w   = (const float*)d_in[2];
    const float* conv_b   = (const float*)d_in[3];
    const float* dt_bias  = (const float*)d_in[4];
    const float* A_log    = (const float*)d_in[5];
    const float* Dp       = (const float*)d_in[6];
    const float* norm_w   = (const float*)d_in[7];
    const float* out_proj = (const float*)d_in[8];
    float* out = (float*)d_out;

    char* w = (char*)d_ws;
    auto alloc = [&](size_t bytes) { char* p = w; w += (bytes + 255) & ~(size_t)255; return p; };
    unsigned short* xb    = (unsigned short*)alloc(4096L * 1024 * 2);
    unsigned short* wb    = (unsigned short*)alloc(4384L * 1024 * 2);
    unsigned short* ob    = (unsigned short*)alloc(1024L * 2048 * 2);
    unsigned short* projT = (unsigned short*)alloc(4384L * 4096 * 2);
    float*          dtraw = (float*)        alloc(4096L * 32 * 4);
    float*          dtv   = (float*)        alloc(64L * 2048 * 4);
    float*          Acum  = (float*)        alloc(64L * 2048 * 4);
    float*          Atot  = (float*)        alloc(64L * 8 * 4);
    unsigned short* xdtT  = (unsigned short*)alloc(2048L * 4096 * 2);
    unsigned short* xdtd  = (unsigned short*)alloc(2048L * 4096 * 2);
    unsigned short* Bb    = (unsigned short*)alloc(4096L * 128 * 2);
    unsigned short* Cb    = (unsigned short*)alloc(4096L * 128 * 2);
    unsigned short* BT    = (unsigned short*)alloc(128L * 4096 * 2);
    unsigned short* Gmb   = (unsigned short*)alloc(16L * 256 * 256 * 2);
    float*          states= (float*)        alloc(2L * 8 * 2048 * 128 * 4);
    unsigned short* prevb = (unsigned short*)alloc(2L * 8 * 2048 * 128 * 2);
    unsigned short* ynu   = (unsigned short*)alloc(4096L * 2048 * 2);
    float*          ssq   = (float*)        alloc(4096L * 4);

    hipMemsetAsync(ssq, 0, 4096 * 4, stream);

    cast3_kernel<<<2048, 256, 0, stream>>>(x, xb, 4096L * 1024 / 8,
                                           in_proj, wb, 4384L * 1024 / 8,
                                           out_proj, ob, 1024L * 2048 / 8);

    // in_proj -> projT + dtraw. 2D XCD partition: gr=4 (rows_per=8, cols_per=18), grid 8*8*18=1152
    gemm_nt<3><<<dim3(1152, 1, 1), 256, 0, stream>>>(
        xb, 1024, 0, 0, wb, 1024, 0, 0, projT, 4096, 0, 0, dtraw,
        4096, 4384, 1024, 32, 35, 4);

    dtcum_kernel<<<512, 256, 0, stream>>>(dtraw, dt_bias, A_log, dtv, Acum, Atot);

    convT_kernel<<<dim3(8, 36, 2), 256, 0, stream>>>(
        projT, conv_w, conv_b, dtv, Acum, Atot, xdtT, xdtd, Bb, Cb, BT);

    // Gm = C B^T per (b,c), bf16 (identity block mapping)
    gemm_nt<1><<<dim3(4, 8, 2), 256, 0, stream>>>(
        Cb, 128, 256L * 128, 2048L * 128,
        Bb, 128, 256L * 128, 2048L * 128,
        Gmb, 256, 256L * 256, 8L * 256 * 256, nullptr,
        256, 256, 128, 2, 2, 0);

    // states[hp][n] = sum_t xdtd[hp][t] BT[n][t] (identity mapping)
    gemm_nt<0><<<dim3(16, 8, 2), 256, 0, stream>>>(
        xdtd, 4096, 256, 2048,
        BT, 4096, 256, 2048,
        states, 128, 2048L * 128, 8L * 2048 * 128, nullptr,
        2048, 128, 256, 16, 1, 0);

    scan_kernel<<<512, 256, 0, stream>>>(states, Atot, prevb);

    ydiagoff_kernel<<<512, 256, 0, stream>>>(Gmb, Acum, xdtT, projT, Cb, prevb,
                                             dtv, Dp, norm_w, ynu, ssq);

    // out = (ynu @ ob^T) * rsqrt(ssq/2048+eps). gr=4 (rows_per=8, cols_per=4), grid 256
    gemm_nt<4><<<dim3(256, 1, 1), 256, 0, stream>>>(
        ynu, 2048, 0, 0, ob, 2048, 0, 0, out, 1024, 0, 0, ssq,
        4096, 1024, 2048, 32, 8, 4);
}